// Round 2
// baseline (42.418 us; speedup 1.0000x reference)
//
#include <hip/hip_runtime.h>
#include <math.h>

#define EDGE_DIM 3
#define NUM_HEADS 8
#define HIDDEN 16

typedef float float4v __attribute__((ext_vector_type(4)));

// Pass 1: zero the dense (N*N*8) f32 output at HBM write ceiling.
// Grid-stride, 16B nontemporal stores.
__global__ void k_zero(float4v* __restrict__ out, size_t n4) {
    size_t i = (size_t)blockIdx.x * blockDim.x + threadIdx.x;
    size_t stride = (size_t)gridDim.x * blockDim.x;
    float4v z = {0.0f, 0.0f, 0.0f, 0.0f};
    for (; i < n4; i += stride) {
        __builtin_nontemporal_store(z, &out[i]);
    }
}

// Per-edge tiny MLP: (3) -> (16) relu -> (8)
__device__ __forceinline__ void edge_mlp(const float a0, const float a1, const float a2,
                                         const float* __restrict__ W1,
                                         const float* __restrict__ b1,
                                         const float* __restrict__ W2,
                                         const float* __restrict__ b2,
                                         float* o /* [NUM_HEADS] */) {
    float h[HIDDEN];
#pragma unroll
    for (int j = 0; j < HIDDEN; ++j) {
        float s = b1[j];
        s += a0 * W1[0 * HIDDEN + j];
        s += a1 * W1[1 * HIDDEN + j];
        s += a2 * W1[2 * HIDDEN + j];
        h[j] = s > 0.0f ? s : 0.0f;
    }
#pragma unroll
    for (int i = 0; i < NUM_HEADS; ++i) {
        float s = b2[i];
#pragma unroll
        for (int j = 0; j < HIDDEN; ++j) s += h[j] * W2[j * NUM_HEADS + i];
        o[i] = s;
    }
}

// Pass 2: deterministic winner per (src,dst) slot = max edge index
// (matches JAX scatter last-write-wins). Marker (e+1) stored as uint in
// word 0 of the zeroed slot.
__global__ void k_mark(const int* __restrict__ ei, float* __restrict__ out,
                       int E, int N) {
    int e = blockIdx.x * blockDim.x + threadIdx.x;
    if (e >= E) return;
    int src = ei[e];
    int dst = ei[E + e];
    size_t slot = (size_t)src * (size_t)N + (size_t)dst;
    unsigned* p = (unsigned*)(out + slot * NUM_HEADS);
    atomicMax(p, (unsigned)(e + 1));
}

// Pass 3 (fused): each edge re-reads the marker; only the winner computes the
// MLP and writes all 8 words. Safety of the word-0 overwrite: a losing
// duplicate reading word 0 concurrently sees either the winner's marker
// (w+1 != its own e+1 since edge ids are unique) or the winner's final float
// value, whose bit pattern we flush away from [1, E] (those are denormals
// < 1e-40, error far below threshold) — both cause it to correctly lose.
__global__ void k_write(const int* __restrict__ ei, const float* __restrict__ ea,
                        const float* __restrict__ W1, const float* __restrict__ b1,
                        const float* __restrict__ W2, const float* __restrict__ b2,
                        float* __restrict__ out, int E, int N) {
    int e = blockIdx.x * blockDim.x + threadIdx.x;
    if (e >= E) return;
    int src = ei[e];
    int dst = ei[E + e];
    size_t slot = (size_t)src * (size_t)N + (size_t)dst;
    float* p = out + slot * NUM_HEADS;
    unsigned m = *(const unsigned*)p;
    if (m != (unsigned)(e + 1)) return;  // not the winner
    float o[NUM_HEADS];
    edge_mlp(ea[e * EDGE_DIM + 0], ea[e * EDGE_DIM + 1], ea[e * EDGE_DIM + 2],
             W1, b1, W2, b2, o);
    unsigned u = __float_as_uint(o[0]);
    if (u >= 1u && u <= (unsigned)E) o[0] = 0.0f;  // flush marker-aliasing denormals
    float4v lo = {o[0], o[1], o[2], o[3]};
    float4v hi = {o[4], o[5], o[6], o[7]};
    *(float4v*)p = lo;        // slot is 32B-aligned
    *(float4v*)(p + 4) = hi;
}

extern "C" void kernel_launch(void* const* d_in, const int* in_sizes, int n_in,
                              void* d_out, int out_size, void* d_ws, size_t ws_size,
                              hipStream_t stream) {
    const int* ei   = (const int*)d_in[0];    // (2, E) int32
    const float* ea = (const float*)d_in[1];  // (E, 3) f32
    const float* W1 = (const float*)d_in[3];  // (3, 16)
    const float* b1 = (const float*)d_in[4];  // (16,)
    const float* W2 = (const float*)d_in[5];  // (16, 8)
    const float* b2 = (const float*)d_in[6];  // (8,)
    float* out = (float*)d_out;

    const int E = in_sizes[0] / 2;
    const int N = (int)(sqrt((double)(out_size / NUM_HEADS)) + 0.5);

    // Pass 1: custom vectorized zero (the 134 MB roofline term).
    size_t n4 = (size_t)out_size / 4;  // out_size divisible by 4 (8 floats/slot)
    k_zero<<<2048, 256, 0, stream>>>((float4v*)out, n4);

    const int blk = 256;
    const int grid = (E + blk - 1) / blk;
    k_mark<<<grid, blk, 0, stream>>>(ei, out, E, N);
    k_write<<<grid, blk, 0, stream>>>(ei, ea, W1, b1, W2, b2, out, E, N);
}

// Round 3
// 33.059 us; speedup vs baseline: 1.2831x; 1.2831x over previous
//
#include <hip/hip_runtime.h>
#include <math.h>

#define EDGE_DIM 3
#define NUM_HEADS 8
#define HIDDEN 16

typedef float float4v __attribute__((ext_vector_type(4)));

// Per-edge tiny MLP: (3) -> (16) relu -> (8)
__device__ __forceinline__ void edge_mlp(const float a0, const float a1, const float a2,
                                         const float* __restrict__ W1,
                                         const float* __restrict__ b1,
                                         const float* __restrict__ W2,
                                         const float* __restrict__ b2,
                                         float* o /* [NUM_HEADS] */) {
    float h[HIDDEN];
#pragma unroll
    for (int j = 0; j < HIDDEN; ++j) {
        float s = b1[j];
        s += a0 * W1[0 * HIDDEN + j];
        s += a1 * W1[1 * HIDDEN + j];
        s += a2 * W1[2 * HIDDEN + j];
        h[j] = s > 0.0f ? s : 0.0f;
    }
#pragma unroll
    for (int i = 0; i < NUM_HEADS; ++i) {
        float s = b2[i];
#pragma unroll
        for (int j = 0; j < HIDDEN; ++j) s += h[j] * W2[j * NUM_HEADS + i];
        o[i] = s;
    }
}

// Pass 2: deterministic winner per (src,dst) slot = max edge index
// (matches JAX scatter last-write-wins). Marker (e+1) stored as uint in
// word 0 of the zeroed slot.
__global__ void k_mark(const int* __restrict__ ei, float* __restrict__ out,
                       int E, int N) {
    int e = blockIdx.x * blockDim.x + threadIdx.x;
    if (e >= E) return;
    int src = ei[e];
    int dst = ei[E + e];
    size_t slot = (size_t)src * (size_t)N + (size_t)dst;
    unsigned* p = (unsigned*)(out + slot * NUM_HEADS);
    atomicMax(p, (unsigned)(e + 1));
}

// Pass 3 (fused): each edge re-reads the marker; only the winner computes the
// MLP and writes all 8 words. Safety of the word-0 overwrite: a losing
// duplicate reading word 0 concurrently sees either the winner's marker
// (w+1 != its own e+1 since edge ids are unique) or the winner's final float
// value, whose bit pattern we flush away from [1, E] (those are denormals
// < 1e-40, error far below threshold) — both cause it to correctly lose.
__global__ void k_write(const int* __restrict__ ei, const float* __restrict__ ea,
                        const float* __restrict__ W1, const float* __restrict__ b1,
                        const float* __restrict__ W2, const float* __restrict__ b2,
                        float* __restrict__ out, int E, int N) {
    int e = blockIdx.x * blockDim.x + threadIdx.x;
    if (e >= E) return;
    int src = ei[e];
    int dst = ei[E + e];
    size_t slot = (size_t)src * (size_t)N + (size_t)dst;
    float* p = out + slot * NUM_HEADS;
    unsigned m = *(const unsigned*)p;
    if (m != (unsigned)(e + 1)) return;  // not the winner
    float o[NUM_HEADS];
    edge_mlp(ea[e * EDGE_DIM + 0], ea[e * EDGE_DIM + 1], ea[e * EDGE_DIM + 2],
             W1, b1, W2, b2, o);
    unsigned u = __float_as_uint(o[0]);
    if (u >= 1u && u <= (unsigned)E) o[0] = 0.0f;  // flush marker-aliasing denormals
    float4v lo = {o[0], o[1], o[2], o[3]};
    float4v hi = {o[4], o[5], o[6], o[7]};
    *(float4v*)p = lo;        // slot is 32B-aligned
    *(float4v*)(p + 4) = hi;
}

extern "C" void kernel_launch(void* const* d_in, const int* in_sizes, int n_in,
                              void* d_out, int out_size, void* d_ws, size_t ws_size,
                              hipStream_t stream) {
    const int* ei   = (const int*)d_in[0];    // (2, E) int32
    const float* ea = (const float*)d_in[1];  // (E, 3) f32
    const float* W1 = (const float*)d_in[3];  // (3, 16)
    const float* b1 = (const float*)d_in[4];  // (16,)
    const float* W2 = (const float*)d_in[5];  // (16, 8)
    const float* b2 = (const float*)d_in[6];  // (8,)
    float* out = (float*)d_out;

    const int E = in_sizes[0] / 2;
    const int N = (int)(sqrt((double)(out_size / NUM_HEADS)) + 0.5);

    // Pass 1: zero the dense output. The graph-captured memset node is the
    // fastest 134 MB zero measured (round 2's custom nt-store kernel was
    // ~5 µs slower) — keep it.
    hipMemsetAsync(d_out, 0, (size_t)out_size * sizeof(float), stream);

    const int blk = 256;
    const int grid = (E + blk - 1) / blk;
    k_mark<<<grid, blk, 0, stream>>>(ei, out, E, N);
    k_write<<<grid, blk, 0, stream>>>(ei, ea, W1, b1, W2, b2, out, E, N);
}